// Round 11
// baseline (92.662 us; speedup 1.0000x reference)
//
#include <hip/hip_runtime.h>
#include <stdint.h>

#define NC 12
#define NHW (256*256)
#define RSTR 72             // LDS floats per tap-row: [3]=haloL, [4..67]=cols, [68]=haloR
#define CSTR 432            // 6*RSTR; CSTR%32==16 -> tap reads exactly 2-way (free, m136)

typedef __attribute__((ext_vector_type(8))) short bf16x8;
typedef __attribute__((ext_vector_type(4))) float f32x4;
typedef __attribute__((ext_vector_type(4))) uint32_t u32x4;
typedef __attribute__((ext_vector_type(2))) __bf16 bf16x2v;

// hot-path pack: single v_cvt_pk_bf16_f32 (suspected hidden-VALU source: scalar
// __bf16 casts may lower to a multi-op RNE sequence)
__device__ __forceinline__ uint32_t pkbf(float lo, float hi) {
    uint32_t r;
    asm("v_cvt_pk_bf16_f32 %0, %1, %2" : "=v"(r) : "v"(lo), "v"(hi));
    return r;
}
// cold-path pack (weight setup, runs once)
__device__ __forceinline__ uint32_t pkbf_c(float lo, float hi) {
    bf16x2v v = { (__bf16)lo, (__bf16)hi };
    return __builtin_bit_cast(uint32_t, v);
}
// opaque pin: keeps weight fragments register-resident across the body
#define PIN(v) asm volatile("" : "+v"(v))

// Fused NCA step, LDS-staged 4x64 tile (half of r9/r10's LDS -> 7 blocks/CU).
// K-bijections (same on A and B => contraction exact):
//   GEMM1 (w1[96x48]·yT): slot(s,g,j): s=0 -> col 12g+j ; s=1,j<4 -> col 12g+8+j
//   GEMM2 (w2[12x96]·hT): slot(s2,g,j) -> col 32s2 + 16*(j>=4) + 4g + (j&3)
// GEMM1's D regs ARE GEMM2's B-frags (no exchange). GEMM2 M-permutation
// sigma(4g+r)=3g+r makes acc2[r]'s out-channel == this lane's stencil channel
// c0+r, so the epilogue's x value is the already-held center tap v4 (zero
// extra LDS reads, all 64 lanes store).
__global__ __launch_bounds__(256, 4) void nca_fused10(
    const float* __restrict__ x, const float* __restrict__ w1,
    const float* __restrict__ b1, const float* __restrict__ w2,
    const float* __restrict__ rmask, float* __restrict__ out)
{
    __shared__ float smem[12 * CSTR];   // 20736 B

    const int tid  = threadIdx.x;
    const int lane = tid & 63;
    const int wv   = tid >> 6;
    const int g    = lane >> 4;   // 16-lane group
    const int p    = lane & 15;   // pixel col (B/D), weight row (A)
    const int c0   = 3 * g;       // this lane's first perception channel

    // ---- resident weight fragments + bias, pinned ----
    u32x4 a1u[6][2];
    f32x4 biasv[6];
    #pragma unroll
    for (int t = 0; t < 6; ++t) {
        const int row = 16*t + p;
        const float4 fa = *reinterpret_cast<const float4*>(w1 + row*48 + 12*g + 0);
        const float4 fb = *reinterpret_cast<const float4*>(w1 + row*48 + 12*g + 4);
        const float4 fc = *reinterpret_cast<const float4*>(w1 + row*48 + 12*g + 8);
        a1u[t][0] = (u32x4){ pkbf_c(fa.x, fa.y), pkbf_c(fa.z, fa.w), pkbf_c(fb.x, fb.y), pkbf_c(fb.z, fb.w) };
        a1u[t][1] = (u32x4){ pkbf_c(fc.x, fc.y), pkbf_c(fc.z, fc.w), 0u, 0u };
        biasv[t] = *reinterpret_cast<const f32x4*>(b1 + 16*t + 4*g);
        PIN(a1u[t][0]); PIN(a1u[t][1]); PIN(biasv[t]);
    }
    // GEMM2 A, M-permuted: A-row m holds w2 row 3*(m>>2)+(m&3) when (m&3)<3
    u32x4 a2u[3];
    {
        const int rp = p & 3, gp = p >> 2;
        const int chA = 3*gp + rp;
        #pragma unroll
        for (int s = 0; s < 3; ++s) {
            u32x4 u = {0u, 0u, 0u, 0u};
            if (rp < 3) {
                const float4 wa = *reinterpret_cast<const float4*>(w2 + chA*96 + 32*s + 4*g);
                const float4 wb = *reinterpret_cast<const float4*>(w2 + chA*96 + 32*s + 16 + 4*g);
                u = (u32x4){ pkbf_c(wa.x, wa.y), pkbf_c(wa.z, wa.w), pkbf_c(wb.x, wb.y), pkbf_c(wb.z, wb.w) };
            }
            a2u[s] = u;
            PIN(a2u[s]);
        }
    }

    // grid: 8192 blocks = 32 batches x 64 row-strips x 4 col-quarters
    const int b    = blockIdx.x >> 8;
    const int rem  = blockIdx.x & 255;
    const int ra   = (rem >> 2) << 2;   // first output row
    const int c0q  = (rem & 3) << 6;    // first output col
    const float* __restrict__ xb = x + (size_t)b * NC * NHW;
    const float* __restrict__ mb = rmask + (size_t)b * NHW;
    float* __restrict__ ob = out + (size_t)b * NC * NHW;

    // ---- stage 12ch x 6 tap-rows x (64 + 2 halo) cols, f32 ----
    {
        #pragma unroll
        for (int k = 0; k < 5; ++k) {
            const int u = tid + (k << 8);       // 1152 main units (16B each)
            if (k < 4 || tid < 128) {
                const int pair  = u >> 4;       // 0..71 = (ch, tap-row)
                const int chunk = u & 15;
                const int c  = pair / 6;
                const int r_ = pair - 6*c;
                const int row = (ra + 255 + r_) & 255;
                const f32x4 v = *reinterpret_cast<const f32x4*>(xb + c*NHW + (row << 8) + c0q + (chunk << 2));
                *reinterpret_cast<f32x4*>(&smem[c*CSTR + r_*RSTR + 4 + (chunk << 2)]) = v;
            }
        }
        if (tid < 144) {                        // 72 pairs x 2 wrap-halo cols
            const int hr  = tid >> 1;
            const int side= tid & 1;
            const int c   = hr / 6;
            const int r_  = hr - 6*c;
            const int row = (ra + 255 + r_) & 255;
            const int col = side ? ((c0q + 64) & 255) : ((c0q + 255) & 255);
            smem[c*CSTR + r_*RSTR + (side ? 68 : 3)] = xb[c*NHW + (row << 8) + col];
        }
    }
    __syncthreads();

    // wave wv owns output row ra+wv; tap rows are slots wv, wv+1, wv+2
    const int h    = ra + wv;
    const int hrow = h << 8;

    // hoisted bases: inner loop uses ONLY immediate offsets
    int tb[3];
    #pragma unroll
    for (int ci = 0; ci < 3; ++ci) tb[ci] = (c0 + ci)*CSTR + wv*RSTR + 3 + p;
    float* obp[3];
    #pragma unroll
    for (int r = 0; r < 3; ++r) obp[r] = ob + (c0 + r)*NHW + hrow + c0q + p;
    const float* mbp = mb + hrow + c0q + p;

    #pragma unroll
    for (int grp = 0; grp < 4; ++grp) {
        const int o = grp << 4;   // compile-time: all accesses below are base+imm

        // ---- perception from LDS, CSE form; keep center taps for epilogue ----
        uint32_t yw[6];
        float xm[3];
        #pragma unroll
        for (int ci = 0; ci < 3; ++ci) {
            const int tbc = tb[ci] + o;
            const float v0 = smem[tbc+0],        v1 = smem[tbc+1],        v2 = smem[tbc+2];
            const float v3 = smem[tbc+RSTR],     v4 = smem[tbc+RSTR+1],   v5 = smem[tbc+RSTR+2];
            const float v6 = smem[tbc+2*RSTR],   v7 = smem[tbc+2*RSTR+1], v8 = smem[tbc+2*RSTR+2];
            const float s0 = v0 + v2, d0 = v2 - v0;
            const float s1 = v3 + v5, d1 = v5 - v3;
            const float s2 = v6 + v8, d2 = v8 - v6;
            const float t0 = fmaf(2.f, v1, s0);
            const float t2 = fmaf(2.f, v7, s2);
            const float fsx = fmaf(2.f, d1, d0 + d2);
            const float fsy = t2 - t0;
            const float lap = fmaf(-12.f, v4, fmaf(2.f, s1, t0 + t2));
            yw[2*ci]   = pkbf(v4, fsx);   // ident, sobel_x
            yw[2*ci+1] = pkbf(fsy, lap);  // sobel_xT, lap
            xm[ci] = v4;
        }
        const bf16x8 yf0 = __builtin_bit_cast(bf16x8, (u32x4){yw[0], yw[1], yw[2], yw[3]});
        const bf16x8 yf1 = __builtin_bit_cast(bf16x8, (u32x4){yw[4], yw[5], 0u, 0u});

        // ---- GEMM1 (bias C-in, ReLU, pack) + GEMM2, MFMA cluster prioritized ----
        __builtin_amdgcn_s_setprio(1);
        uint32_t pu[6][2];
        #pragma unroll
        for (int t = 0; t < 6; ++t) {
            f32x4 acc = biasv[t];
            acc = __builtin_amdgcn_mfma_f32_16x16x32_bf16(__builtin_bit_cast(bf16x8, a1u[t][0]), yf0, acc, 0, 0, 0);
            acc = __builtin_amdgcn_mfma_f32_16x16x32_bf16(__builtin_bit_cast(bf16x8, a1u[t][1]), yf1, acc, 0, 0, 0);
            pu[t][0] = pkbf(fmaxf(acc[0], 0.f), fmaxf(acc[1], 0.f));
            pu[t][1] = pkbf(fmaxf(acc[2], 0.f), fmaxf(acc[3], 0.f));
        }
        f32x4 acc2 = {0.f, 0.f, 0.f, 0.f};
        #pragma unroll
        for (int s2 = 0; s2 < 3; ++s2) {
            const u32x4 fb2 = { pu[2*s2][0], pu[2*s2][1], pu[2*s2+1][0], pu[2*s2+1][1] };
            acc2 = __builtin_amdgcn_mfma_f32_16x16x32_bf16(__builtin_bit_cast(bf16x8, a2u[s2]), __builtin_bit_cast(bf16x8, fb2), acc2, 0, 0, 0);
        }
        __builtin_amdgcn_s_setprio(0);

        // ---- epilogue: x comes from the held center taps; all 64 lanes store ----
        const float um = floorf(mbp[o] + 0.5f);
        #pragma unroll
        for (int r = 0; r < 3; ++r)
            obp[r][o] = xm[r] + acc2[r] * um;
    }
}

extern "C" void kernel_launch(void* const* d_in, const int* in_sizes, int n_in,
                              void* d_out, int out_size, void* d_ws, size_t ws_size,
                              hipStream_t stream) {
    const float* x  = (const float*)d_in[0];
    const float* w1 = (const float*)d_in[1];
    const float* b1 = (const float*)d_in[2];
    const float* w2 = (const float*)d_in[3];
    const float* rm = (const float*)d_in[4];
    float* out = (float*)d_out;
    nca_fused10<<<dim3(32 * 64 * 4), dim3(256), 0, stream>>>(x, w1, b1, w2, rm, out);
}